// Round 1
// 1991.928 us; speedup vs baseline: 1.0544x; 1.0544x over previous
//
#include <hip/hip_runtime.h>
#include <hip/hip_bf16.h>
#include <cstdint>
#include <cstddef>

#define IN_DIM 4096
#define OUT_DIM 32768
#define BATCH 4096
#define EPS 1e-8f

typedef __attribute__((ext_vector_type(4))) float f32x4;
typedef __attribute__((ext_vector_type(8))) short bf16x8;
typedef __attribute__((ext_vector_type(4))) unsigned int u32x4;

__device__ __forceinline__ unsigned short f2bf(float f) {
    union { float f; unsigned int u; } v;
    v.f = f;
    unsigned int u = v.u;
    unsigned int r = (u + 0x7FFFu + ((u >> 16) & 1u)) >> 16;
    return (unsigned short)r;
}

__device__ __forceinline__ void load_lds16(const void* g, void* l) {
    __builtin_amdgcn_global_load_lds(
        (const __attribute__((address_space(1))) void*)g,
        (__attribute__((address_space(3))) void*)l,
        16, 0, 0);
}

// ---------------------------------------------------------------------------
// Kernel 1: x fp32 -> bf16 + per-row inverse norms. (unchanged - already fast)
// ---------------------------------------------------------------------------
__global__ void xprep(const float* __restrict__ x,
                      unsigned short* __restrict__ xb,
                      float* __restrict__ xinv) {
    const int row = blockIdx.x;
    const int tid = threadIdx.x;
    const float4* x4 = (const float4*)(x + (size_t)row * IN_DIM);
    ushort4* xb4 = (ushort4*)(xb + (size_t)row * IN_DIM);
    float ss = 0.f;
#pragma unroll
    for (int it = 0; it < IN_DIM / 4 / 256; ++it) {
        int i = it * 256 + tid;
        float4 v = x4[i];
        ss += v.x * v.x + v.y * v.y + v.z * v.z + v.w * v.w;
        ushort4 o;
        o.x = f2bf(v.x); o.y = f2bf(v.y); o.z = f2bf(v.z); o.w = f2bf(v.w);
        xb4[i] = o;
    }
#pragma unroll
    for (int off = 32; off > 0; off >>= 1) ss += __shfl_down(ss, off);
    __shared__ float red[4];
    if ((tid & 63) == 0) red[tid >> 6] = ss;
    __syncthreads();
    if (tid == 0) {
        float s = red[0] + red[1] + red[2] + red[3];
        xinv[row] = 1.f / fmaxf(sqrtf(s), EPS);
    }
}

// ---------------------------------------------------------------------------
// Kernel 2 (rewritten): w (IN_DIM x OUT_DIM fp32) -> bf16 transposed wt
// (OUT_DIM x IN_DIM) + column sum-of-squares.
// Block: 256 threads, covers 64 cols x 512 K-rows. float4 loads, 16B/lane
// transposed stores via LDS tile, register col-sums, 8 atomics/col total.
// ---------------------------------------------------------------------------
__global__ void wprep(const float* __restrict__ w,
                      unsigned short* __restrict__ wt,
                      float* __restrict__ wn2) {
    __shared__ unsigned int tile32[64][33];  // 64 k-rows x 64 cols (bf16 pairs)
    __shared__ f32x4 csum[256];
    const int t = threadIdx.x;
    const int j0 = blockIdx.x * 64;
    const int kb = blockIdx.y * 512;
    const int c4 = t & 15;   // col group (float4)
    const int ir = t >> 4;   // 0..15
    f32x4 ss = {0.f, 0.f, 0.f, 0.f};
#pragma unroll 1
    for (int tk = 0; tk < 8; ++tk) {
        const int i0 = kb + tk * 64;
#pragma unroll
        for (int p = 0; p < 4; ++p) {
            int il = p * 16 + ir;
            const float4 v = *(const float4*)(w + (size_t)(i0 + il) * OUT_DIM + j0 + c4 * 4);
            ss[0] += v.x * v.x; ss[1] += v.y * v.y;
            ss[2] += v.z * v.z; ss[3] += v.w * v.w;
            tile32[il][c4 * 2]     = (unsigned int)f2bf(v.x) | ((unsigned int)f2bf(v.y) << 16);
            tile32[il][c4 * 2 + 1] = (unsigned int)f2bf(v.z) | ((unsigned int)f2bf(v.w) << 16);
        }
        __syncthreads();
        // transposed write: 16B per lane, 8 lanes per output row
#pragma unroll
        for (int e = 0; e < 2; ++e) {
            int idx = e * 256 + t;
            int jj = idx >> 3;
            int ch = idx & 7;
            unsigned int sh = (jj & 1) * 16;
            int cc = jj >> 1;
            unsigned int u0 = (tile32[ch * 8 + 0][cc] >> sh) & 0xffffu;
            unsigned int u1 = (tile32[ch * 8 + 1][cc] >> sh) & 0xffffu;
            unsigned int u2 = (tile32[ch * 8 + 2][cc] >> sh) & 0xffffu;
            unsigned int u3 = (tile32[ch * 8 + 3][cc] >> sh) & 0xffffu;
            unsigned int u4 = (tile32[ch * 8 + 4][cc] >> sh) & 0xffffu;
            unsigned int u5 = (tile32[ch * 8 + 5][cc] >> sh) & 0xffffu;
            unsigned int u6 = (tile32[ch * 8 + 6][cc] >> sh) & 0xffffu;
            unsigned int u7 = (tile32[ch * 8 + 7][cc] >> sh) & 0xffffu;
            u32x4 o;
            o[0] = u0 | (u1 << 16); o[1] = u2 | (u3 << 16);
            o[2] = u4 | (u5 << 16); o[3] = u6 | (u7 << 16);
            *(u32x4*)(wt + (size_t)(j0 + jj) * IN_DIM + i0 + ch * 8) = o;
        }
        __syncthreads();
    }
    csum[t] = ss;
    __syncthreads();
    if (t < 16) {
        f32x4 a = csum[t];
#pragma unroll
        for (int g = 1; g < 16; ++g) a += csum[t + 16 * g];
        atomicAdd(&wn2[j0 + t * 4 + 0], a[0]);
        atomicAdd(&wn2[j0 + t * 4 + 1], a[1]);
        atomicAdd(&wn2[j0 + t * 4 + 2], a[2]);
        atomicAdd(&wn2[j0 + t * 4 + 3], a[3]);
    }
}

// ---------------------------------------------------------------------------
// Kernel 3: wn2 -> inverse norms
// ---------------------------------------------------------------------------
__global__ void wfin(const float* __restrict__ wn2, float* __restrict__ winv) {
    int j = blockIdx.x * 256 + threadIdx.x;
    winv[j] = 1.f / fmaxf(sqrtf(wn2[j]), EPS);
}

// ---------------------------------------------------------------------------
// Kernel 4: GEMM, 256x256 tile, BK=32, 8 waves (2M x 4N), quad-buffered LDS
// (4 x 32KB), phase-split schedule with counted vmcnt (T1+T2+T3+T4+T5).
// LDS layout XOR-swizzled: byte(r,q) = (r<<6) ^ (((r&7)^q)<<4); staging uses
// linear LDS dest + inverse-swizzled per-lane GLOBAL source (rule #21).
// ---------------------------------------------------------------------------
#define BM 256
#define BN 256
#define BK 32
#define NT (IN_DIM / BK)      // 128
#define TILE_BYTES 16384      // one 256x32 bf16 tile
#define BUF_BYTES 32768       // A tile + B tile

__launch_bounds__(512, 2)
__global__ void gemm_kernel(const unsigned short* __restrict__ A,
                            const unsigned short* __restrict__ B,
                            float* __restrict__ C,
                            const float* __restrict__ xinv,
                            const float* __restrict__ winv) {
    extern __shared__ char smem[];
    const int tid = threadIdx.x;
    const int wave = tid >> 6;
    const int lane = tid & 63;
    const int ml = lane & 15;
    const int quad = lane >> 4;

    // XCD-aware bijective swizzle (2048 blocks % 8 == 0)
    const int bid = blockIdx.x;
    const int swz = (bid & 7) * 256 + (bid >> 3);
    const int m0 = (swz & 15) * BM;   // 16 M-tiles
    const int n0 = (swz >> 4) * BN;   // 128 N-tiles

    const int wm = (wave >> 2) * 128; // 0 or 128
    const int wn = (wave & 3) * 64;   // 0,64,128,192

    // staging: chunk p -> (row r, kchunk q), inverse of the read swizzle.
    // R=p>>2, Qlin=p&3; r0 = R0^R2; r = (R&~1)|r0; q = Qlin ^ ((R&2)|r0)
    const int p0 = tid;
    const int Ra = p0 >> 2, Qa = p0 & 3;
    const int r0b = (Ra ^ (Ra >> 2)) & 1;
    const int rA0 = (Ra & ~1) | r0b;
    const int qA0 = Qa ^ ((Ra & 2) | r0b);
    const int p1 = tid + 512;
    const int Rb = p1 >> 2, Qb = p1 & 3;
    const int r1b = (Rb ^ (Rb >> 2)) & 1;
    const int rA1 = (Rb & ~1) | r1b;
    const int qA1 = Qb ^ ((Rb & 2) | r1b);

    const unsigned short* gA0 = A + (size_t)(m0 + rA0) * IN_DIM + qA0 * 8;
    const unsigned short* gA1 = A + (size_t)(m0 + rA1) * IN_DIM + qA1 * 8;
    const unsigned short* gB0 = B + (size_t)(n0 + rA0) * IN_DIM + qA0 * 8;
    const unsigned short* gB1 = B + (size_t)(n0 + rA1) * IN_DIM + qA1 * 8;

    // wave-uniform LDS chunk bases (HW adds lane*16)
    const int dst0 = wave * 1024;
    const int dst1 = 8192 + wave * 1024;

    // fragment read offsets: byte = ((row<<6) ^ (((ml&7)^quad)<<4)) since row&7==ml&7
    const int sw = (((ml & 7) ^ quad) << 4);
    const int aoff = ((wm + ml) << 6) ^ sw;
    const int boff = ((wn + ml) << 6) ^ sw;

    f32x4 acc[8][4] = {};

    // prologue: stage tiles 0..2 (A0,A1,B0,B1 each: 12 loads total)
#pragma unroll
    for (int tt = 0; tt < 3; ++tt) {
        char* sb = smem + tt * BUF_BYTES;
        load_lds16(gA0 + tt * BK, sb + dst0);
        load_lds16(gA1 + tt * BK, sb + dst1);
        load_lds16(gB0 + tt * BK, sb + TILE_BYTES + dst0);
        load_lds16(gB1 + tt * BK, sb + TILE_BYTES + dst1);
    }
    asm volatile("s_waitcnt vmcnt(8)" ::: "memory");  // tile 0 landed
    __builtin_amdgcn_sched_barrier(0);
    __builtin_amdgcn_s_barrier();
    __builtin_amdgcn_sched_barrier(0);

    int koff = 3 * BK;
    for (int t = 0; t < NT; ++t) {
        const char* ta = smem + (t & 3) * BUF_BYTES;
        const char* tb = ta + TILE_BYTES;
        char* sb = smem + ((t + 3) & 3) * BUF_BYTES;
        const bool st = (t + 3) < NT;

        // ---------------- phase 1: C rows wm..wm+63 ----------------
        bf16x8 af[4], bfr[4];
#pragma unroll
        for (int i = 0; i < 4; ++i)
            af[i] = *(const bf16x8*)(ta + aoff + i * 1024);
#pragma unroll
        for (int j = 0; j < 4; ++j)
            bfr[j] = *(const bf16x8*)(tb + boff + j * 1024);
        if (st) {
            load_lds16(gA0 + koff, sb + dst0);
            load_lds16(gA1 + koff, sb + dst1);
        }
        __builtin_amdgcn_s_barrier();
        asm volatile("s_waitcnt lgkmcnt(0)" ::: "memory");
        __builtin_amdgcn_s_setprio(1);
#pragma unroll
        for (int i = 0; i < 4; ++i)
#pragma unroll
            for (int j = 0; j < 4; ++j)
                acc[i][j] = __builtin_amdgcn_mfma_f32_16x16x32_bf16(
                    af[i], bfr[j], acc[i][j], 0, 0, 0);
        __builtin_amdgcn_s_setprio(0);
        __builtin_amdgcn_s_barrier();

        // ---------------- phase 2: C rows wm+64..wm+127 ----------------
        bf16x8 ag[4];
#pragma unroll
        for (int i = 0; i < 4; ++i)
            ag[i] = *(const bf16x8*)(ta + aoff + 4096 + i * 1024);
        if (st) {
            load_lds16(gB0 + koff, sb + TILE_BYTES + dst0);
            load_lds16(gB1 + koff, sb + TILE_BYTES + dst1);
        }
        __builtin_amdgcn_s_barrier();
        asm volatile("s_waitcnt lgkmcnt(0)" ::: "memory");
        __builtin_amdgcn_s_setprio(1);
#pragma unroll
        for (int i = 0; i < 4; ++i)
#pragma unroll
            for (int j = 0; j < 4; ++j)
                acc[4 + i][j] = __builtin_amdgcn_mfma_f32_16x16x32_bf16(
                    ag[i], bfr[j], acc[4 + i][j], 0, 0, 0);
        __builtin_amdgcn_s_setprio(0);

        // K-tile boundary: counted vmcnt (8 = tiles t+2,t+3 in flight),
        // drains 8 -> 4 -> 0 only at the tail.
        if (t < NT - 3) {
            asm volatile("s_waitcnt vmcnt(8)" ::: "memory");
        } else if (t == NT - 3) {
            asm volatile("s_waitcnt vmcnt(4)" ::: "memory");
        } else if (t == NT - 2) {
            asm volatile("s_waitcnt vmcnt(0)" ::: "memory");
        }
        __builtin_amdgcn_sched_barrier(0);
        __builtin_amdgcn_s_barrier();
        __builtin_amdgcn_sched_barrier(0);
        koff += BK;
    }

    // epilogue: C/D layout col = lane&15, row = quad*4 + r
    float xs[8][4];
#pragma unroll
    for (int i = 0; i < 8; ++i)
#pragma unroll
        for (int r = 0; r < 4; ++r)
            xs[i][r] = xinv[m0 + wm + i * 16 + quad * 4 + r];

#pragma unroll
    for (int j = 0; j < 4; ++j) {
        int n = n0 + wn + j * 16 + ml;
        float wsc = winv[n];
#pragma unroll
        for (int i = 0; i < 8; ++i) {
            int mbase = m0 + wm + i * 16 + quad * 4;
#pragma unroll
            for (int r = 0; r < 4; ++r) {
                C[(size_t)(mbase + r) * OUT_DIM + n] = acc[i][j][r] * wsc * xs[i][r];
            }
        }
    }
}

// ---------------------------------------------------------------------------
extern "C" void kernel_launch(void* const* d_in, const int* in_sizes, int n_in,
                              void* d_out, int out_size, void* d_ws, size_t ws_size,
                              hipStream_t stream) {
    const float* x = (const float*)d_in[0];
    const float* w = (const float*)d_in[1];
    float* out = (float*)d_out;

    char* ws = (char*)d_ws;
    unsigned short* xb = (unsigned short*)ws;                                // 32 MB
    unsigned short* wt = (unsigned short*)(ws + (size_t)BATCH * IN_DIM * 2); // 256 MB
    char* tail = ws + (size_t)BATCH * IN_DIM * 2 + (size_t)OUT_DIM * IN_DIM * 2;
    float* xinv = (float*)tail;
    float* wn2 = xinv + BATCH;
    float* winv = wn2 + OUT_DIM;

    hipMemsetAsync(wn2, 0, OUT_DIM * sizeof(float), stream);
    xprep<<<BATCH, 256, 0, stream>>>(x, xb, xinv);
    wprep<<<dim3(OUT_DIM / 64, IN_DIM / 512), 256, 0, stream>>>(w, wt, wn2);
    wfin<<<OUT_DIM / 256, 256, 0, stream>>>(wn2, winv);

    hipFuncSetAttribute((const void*)gemm_kernel,
                        hipFuncAttributeMaxDynamicSharedMemorySize, 131072);
    gemm_kernel<<<(BATCH / BM) * (OUT_DIM / BN), 512, 131072, stream>>>(
        xb, wt, out, xinv, winv);
}